// Round 1
// 1190.997 us; speedup vs baseline: 1.5289x; 1.5289x over previous
//
#include <hip/hip_runtime.h>
#include <hip/hip_bf16.h>
#include <math.h>

typedef __hip_bfloat16 bf16;
typedef unsigned short u16;
typedef __attribute__((ext_vector_type(4))) float f32x4;
typedef __attribute__((ext_vector_type(8))) __bf16 bfrag;

#define NB   4096
#define DIMK 2048
#define NE   8
#define NH   16
#define HDIM 128
#define W3   6144
#define BK   32
#define WMAX 96   // max work items: sum_p ceil(cnt_p/64) <= 64 + 27 = 91
#define QS   132  // attn q/k/v LDS row stride (floats)
#define ATT_SCALE 0.08838834764831845f

// ---- async global->LDS 16B (dest = wave-uniform base + lane*16) ----
__device__ __forceinline__ void gl16(const bf16* g, u16* l) {
    __builtin_amdgcn_global_load_lds(
        (const __attribute__((address_space(1))) void*)g,
        (__attribute__((address_space(3))) void*)l, 16, 0, 0);
}

// ---- f32 -> bf16 bulk conversion (8 elems/thread, vectorized) ----
__global__ __launch_bounds__(256)
void k_cvt(const float* __restrict__ src, bf16* __restrict__ dst, long long n) {
    long long i = ((long long)blockIdx.x * 256 + threadIdx.x) * 8;
    if (i + 8 <= n) {
        float4 a = *(const float4*)(src + i);
        float4 b = *(const float4*)(src + i + 4);
        bf16 o[8];
        o[0] = __float2bfloat16(a.x); o[1] = __float2bfloat16(a.y);
        o[2] = __float2bfloat16(a.z); o[3] = __float2bfloat16(a.w);
        o[4] = __float2bfloat16(b.x); o[5] = __float2bfloat16(b.y);
        o[6] = __float2bfloat16(b.z); o[7] = __float2bfloat16(b.w);
        *(uint4*)(dst + i) = *(uint4*)o;
    }
}

// ---- f32 -> bf16 TRANSPOSING conversion: dst[e][f][d] = bf16(src[e][d][f])
// 64x64 tiles via LDS; both global sides coalesced.
__global__ __launch_bounds__(256)
void k_cvt_t(const float* __restrict__ src, bf16* __restrict__ dst,
             int ldsrc, int lddst, long long srcE, long long dstE) {
    __shared__ u16 tile[64][65];
    int e = blockIdx.z;
    int d0 = blockIdx.y << 6, f0 = blockIdx.x << 6;
    int t = threadIdx.x;
    const float* S = src + (size_t)e * srcE + (size_t)d0 * ldsrc + f0;
    int dr = t >> 4, fc = (t & 15) << 2;
#pragma unroll
    for (int i = 0; i < 4; i++) {
        float4 v = *(const float4*)(S + (size_t)(dr + (i << 4)) * ldsrc + fc);
        bf16 b0 = __float2bfloat16(v.x), b1 = __float2bfloat16(v.y),
             b2 = __float2bfloat16(v.z), b3 = __float2bfloat16(v.w);
        u16* tp = &tile[dr + (i << 4)][fc];
        tp[0] = *(u16*)&b0; tp[1] = *(u16*)&b1;
        tp[2] = *(u16*)&b2; tp[3] = *(u16*)&b3;
    }
    __syncthreads();
    bf16* D = dst + (size_t)e * dstE + (size_t)f0 * lddst + d0;
#pragma unroll
    for (int r = 0; r < 2; r++) {
        int c = (r << 8) + t;
        int fr = c >> 3, chk = c & 7;
        u16 o[8];
#pragma unroll
        for (int j = 0; j < 8; j++) o[j] = tile[chk * 8 + j][fr];
        *(uint4*)(D + (size_t)fr * lddst + chk * 8) = *(uint4*)o;
    }
}

__global__ void k_zero(int* counts) {
    if (threadIdx.x < 64) counts[threadIdx.x] = 0;
}

// One wave per row, pure f32 (matches np reference selection): logits, softmax,
// top-2, append (row, gates) to PAIR list. Index-clamped so bad data cannot fault.
__global__ void k_gate(const float* __restrict__ x, const float* __restrict__ Wg,
                       const float* __restrict__ bg, int* __restrict__ counts,
                       int* __restrict__ rowsP, float* __restrict__ gA,
                       float* __restrict__ gB) {
    int b = blockIdx.x;
    int l = threadIdx.x;
    float acc[NE];
#pragma unroll
    for (int e = 0; e < NE; e++) acc[e] = 0.f;
    for (int i = 0; i < DIMK / 64; i++) {
        int d = i * 64 + l;
        float xv = x[(size_t)b * DIMK + d];
        const float* wrow = Wg + (size_t)d * NE;
#pragma unroll
        for (int e = 0; e < NE; e++) acc[e] += xv * wrow[e];
    }
#pragma unroll
    for (int e = 0; e < NE; e++)
        for (int off = 32; off > 0; off >>= 1) acc[e] += __shfl_down(acc[e], off);
    if (l == 0) {
        float p[NE]; float m = -1e30f;
        for (int e = 0; e < NE; e++) { p[e] = acc[e] + bg[e]; m = fmaxf(m, p[e]); }
        float s = 0.f;
        for (int e = 0; e < NE; e++) { p[e] = __expf(p[e] - m); s += p[e]; }
        float inv = 1.f / s;
        for (int e = 0; e < NE; e++) p[e] *= inv;
        int i1 = 0; float v1 = p[0];
        for (int e = 1; e < NE; e++) if (p[e] > v1) { v1 = p[e]; i1 = e; }   // first-max = jax tie rule
        int i2 = -1; float v2 = -1.f;
        for (int e = 0; e < NE; e++) if (e != i1 && p[e] > v2) { v2 = p[e]; i2 = e; }
        if (i2 < 0) i2 = (i1 + 1) & 7;   // NaN safety: never out of range
        int a, bb; float ga, gb;
        if (i1 < i2) { a = i1; bb = i2; ga = v1; gb = v2; }
        else         { a = i2; bb = i1; ga = v2; gb = v1; }
        int pid = a * NE + bb;
        pid = pid < 0 ? 0 : (pid > 63 ? 63 : pid);
        int pos = atomicAdd(&counts[pid], 1);
        if (pos < NB) {
            rowsP[pid * NB + pos] = b; gA[pid * NB + pos] = ga; gB[pid * NB + pos] = gb;
        }
    }
}

// Flatten (pair, row-tile) into a compact work list.
__global__ void k_sched(const int* __restrict__ counts, int2* __restrict__ work) {
    if (threadIdx.x == 0) {
        int w = 0;
        for (int p = 0; p < 64; p++) {
            int c = counts[p]; c = c > NB ? NB : c;
            for (int m = 0; m < c && w < WMAX; m += 64) work[w++] = make_int2(p, m);
        }
        for (; w < WMAX; w++) work[w] = make_int2(-1, 0);
    }
}

// Pair-grouped gather-GEMM over the full 6144 W columns.
// Wt layout: [e][n][k] bf16 (k-contiguous) -> pure DMA staging, no transpose.
// Tile: 64 rows x 128 cols x BK=32, 4 waves (each: all 64 rows x 32 cols x 2 experts).
// LDS tiles stored as 128B "lines" = 2 rows x 32 k, 16B chunk swizzled by line&7;
// swizzle applied on BOTH the global source (staging) and the ds_read address ->
// all fragment reads are bank-conflict-free. Double-buffered, 1 barrier/K-step.
__global__ __launch_bounds__(256, 3)
void k_moe(const bf16* __restrict__ xb, const bf16* __restrict__ yb,
           const bf16* __restrict__ Wt, const int* __restrict__ counts,
           const int* __restrict__ rowsP, const float* __restrict__ gAp,
           const float* __restrict__ gBp, const int2* __restrict__ work,
           bf16* __restrict__ qbuf, bf16* __restrict__ kvbuf) {
    int2 wi = work[blockIdx.y];
    if (wi.x < 0) return;
    int p = wi.x, m0 = wi.y;
    int eA = p >> 3, eB = p & 7;
    int cnt = counts[p]; cnt = cnt > NB ? NB : cnt;
    int n0 = blockIdx.x * 128;                // absolute W column
    const bf16* A = (n0 < DIMK) ? yb : xb;
    bf16* outp; int ldc, coff;
    if (n0 < DIMK) { outp = qbuf;  ldc = DIMK;     coff = n0; }
    else           { outp = kvbuf; ldc = 2 * DIMK; coff = n0 - DIMK; }

    __shared__ __align__(16) u16 Al[2][2048];        // 64 rows x 32 k, dbuf
    __shared__ __align__(16) u16 Bl[2][2][4096];     // [buf][expert][128 cols x 32 k]
    __shared__ int   rowb[64];
    __shared__ float ga_s[64], gb_s[64];

    int t = threadIdx.x;
    if (t < 64) {
        int mg = m0 + t;
        if (mg < cnt) {
            int rv = rowsP[p * NB + mg];
            rowb[t] = (rv >= 0 && rv < NB) ? rv : -1;
            ga_s[t] = gAp[p * NB + mg]; gb_s[t] = gBp[p * NB + mg];
        } else { rowb[t] = -1; ga_s[t] = 0.f; gb_s[t] = 0.f; }
    }
    __syncthreads();

    int lane = t & 63, w = t >> 6;
    int q = lane >> 4, lr = lane & 15;
    int wbase = (t & ~63) * 8;   // wave's LDS chunk base (u16 offset)

    // A staging source: 256 chunks (1 round). chunk t -> line t>>3, swizzled slot.
    int aline = t >> 3;
    int as_ = (t & 7) ^ (aline & 7);
    int atrow = aline * 2 + (as_ >> 2);
    int arowg = rowb[atrow];
    const bf16* srcA = A + (size_t)(arowg >= 0 ? arowg : 0) * DIMK + (as_ & 3) * 8;

    // B staging sources: 2 experts x 2 rounds (512 chunks each expert).
    const bf16* srcB0[2]; const bf16* srcB1[2];
#pragma unroll
    for (int r = 0; r < 2; r++) {
        int c = (r << 8) + t;
        int line = c >> 3;
        int s = (c & 7) ^ (line & 7);
        int col = line * 2 + (s >> 2);
        size_t off = (size_t)(n0 + col) * DIMK + (s & 3) * 8;
        srcB0[r] = Wt + (size_t)eA * W3 * DIMK + off;
        srcB1[r] = Wt + (size_t)eB * W3 * DIMK + off;
    }

    f32x4 acc0[2][4], acc1[2][4];   // [nf][m] for expert A / expert B
#pragma unroll
    for (int nf = 0; nf < 2; nf++)
#pragma unroll
        for (int m = 0; m < 4; m++) {
            acc0[nf][m] = (f32x4){0.f,0.f,0.f,0.f};
            acc1[nf][m] = (f32x4){0.f,0.f,0.f,0.f};
        }

#define MOE_STAGE(BUF, K0) do { \
    gl16(srcA + (K0),      &Al[BUF][wbase]); \
    gl16(srcB0[0] + (K0),  &Bl[BUF][0][wbase]); \
    gl16(srcB0[1] + (K0),  &Bl[BUF][0][2048 + wbase]); \
    gl16(srcB1[0] + (K0),  &Bl[BUF][1][wbase]); \
    gl16(srcB1[1] + (K0),  &Bl[BUF][1][2048 + wbase]); \
} while (0)

#define MOE_COMP(BUF) do { \
    bfrag af[4]; \
    _Pragma("unroll") for (int m = 0; m < 4; m++) { \
        int row = m * 16 + lr; int line = row >> 1; \
        af[m] = *(const bfrag*)&Al[BUF][line * 64 + ((((row & 1) << 2) | q) ^ (line & 7)) * 8]; \
    } \
    _Pragma("unroll") for (int nf = 0; nf < 2; nf++) { \
        int col = (w << 5) + (nf << 4) + lr; int line = col >> 1; \
        int bo = line * 64 + ((((col & 1) << 2) | q) ^ (line & 7)) * 8; \
        bfrag b0 = *(const bfrag*)&Bl[BUF][0][bo]; \
        bfrag b1 = *(const bfrag*)&Bl[BUF][1][bo]; \
        _Pragma("unroll") for (int m = 0; m < 4; m++) { \
            acc0[nf][m] = __builtin_amdgcn_mfma_f32_16x16x32_bf16(af[m], b0, acc0[nf][m], 0, 0, 0); \
            acc1[nf][m] = __builtin_amdgcn_mfma_f32_16x16x32_bf16(af[m], b1, acc1[nf][m], 0, 0, 0); \
        } \
    } \
} while (0)

    MOE_STAGE(0, 0);
    __syncthreads();
    for (int k0 = 0; k0 < DIMK; k0 += 2 * BK) {
        MOE_STAGE(1, k0 + BK);
        MOE_COMP(0);
        __syncthreads();
        if (k0 + 2 * BK < DIMK) MOE_STAGE(0, k0 + 2 * BK);
        MOE_COMP(1);
        __syncthreads();
    }
#undef MOE_STAGE
#undef MOE_COMP

#pragma unroll
    for (int nf = 0; nf < 2; nf++) {
        int col = coff + (w << 5) + (nf << 4) + lr;
#pragma unroll
        for (int m = 0; m < 4; m++)
#pragma unroll
            for (int r = 0; r < 4; r++) {
                int tr = m * 16 + q * 4 + r;
                int rb = rowb[tr];
                if (rb >= 0)
                    outp[(size_t)rb * ldc + col] =
                        __float2bfloat16(ga_s[tr] * acc0[nf][m][r] + gb_s[tr] * acc1[nf][m][r]);
            }
    }
}

// Per-row 16x16 head-attention; aout may ALIAS qv (row fully read before write).
__global__ __launch_bounds__(256)
void k_attn(const bf16* qv, const bf16* __restrict__ kv, bf16* aout) {
    int b = blockIdx.x;
    int t = threadIdx.x;
    __shared__ __align__(16) float qs[NH * QS];
    __shared__ __align__(16) float ks[NH * QS];
    __shared__ __align__(16) float vs[NH * QS];
    __shared__ float Ps[NH * 17];
    size_t qb = (size_t)b * DIMK;
    size_t kb = (size_t)b * (2 * DIMK);
    {   // vectorized bf16x8 loads (2048 elems per tensor = 256 threads x 8)
        uint4 q4 = *(const uint4*)(qv + qb + (size_t)t * 8);
        uint4 k4 = *(const uint4*)(kv + kb + (size_t)t * 8);
        uint4 v4 = *(const uint4*)(kv + kb + DIMK + (size_t)t * 8);
        const bf16* qp = (const bf16*)&q4;
        const bf16* kp = (const bf16*)&k4;
        const bf16* vp = (const bf16*)&v4;
        int hh = t >> 4, dd = (t & 15) << 3;
        float* qd = &qs[hh * QS + dd];
        float* kd = &ks[hh * QS + dd];
        float* vd = &vs[hh * QS + dd];
#pragma unroll
        for (int j = 0; j < 8; j++) {
            qd[j] = __bfloat162float(qp[j]);
            kd[j] = __bfloat162float(kp[j]);
            vd[j] = __bfloat162float(vp[j]);
        }
    }
    __syncthreads();
    int h = t >> 4, g = t & 15;
    float s = 0.f;
    for (int i = 0; i < HDIM / 4; i++) {
        float4 q4 = *(const float4*)&qs[h * QS + 4 * i];
        float4 k4 = *(const float4*)&ks[g * QS + 4 * i];
        s += q4.x * k4.x + q4.y * k4.y + q4.z * k4.z + q4.w * k4.w;
    }
    s *= ATT_SCALE;
    float m = s;
    for (int off = 8; off > 0; off >>= 1) m = fmaxf(m, __shfl_xor(m, off, 16));
    float p = __expf(s - m);
    float sum = p;
    for (int off = 8; off > 0; off >>= 1) sum += __shfl_xor(sum, off, 16);
    Ps[h * 17 + g] = p / sum;
    __syncthreads();
#pragma unroll
    for (int j = 0; j < 8; j++) {
        int n = t + 256 * j;                 // flat n = d*16+h (swapaxes folded in)
        int hh = n & 15, dd = n >> 4;
        float o = 0.f;
#pragma unroll
        for (int gg = 0; gg < 16; gg++) o += Ps[hh * 17 + gg] * vs[gg * QS + dd];
        aout[(size_t)b * DIMK + n] = __float2bfloat16(o);
    }
}

// out(f32) = A(bf16) @ Wp + bp;  Wt layout [n][k] (k-contiguous).
// 128x128 tile, 4 waves (2x2 of 64x64), same DMA+swizzle+dbuf machinery as k_moe.
__global__ __launch_bounds__(256, 3)
void k_gemm_bias(const bf16* __restrict__ A, const bf16* __restrict__ Wt,
                 const float* __restrict__ bias, float* __restrict__ out) {
    int m0 = blockIdx.y * 128, n0 = blockIdx.x * 128;
    int t = threadIdx.x;
    __shared__ __align__(16) u16 Al[2][4096];   // 128 rows x 32 k, dbuf
    __shared__ __align__(16) u16 Bl[2][4096];   // 128 cols x 32 k, dbuf
    int lane = t & 63, w = t >> 6;
    int q = lane >> 4, lr = lane & 15;
    int rh = (w >> 1) << 6, chf = (w & 1) << 6;
    int wbase = (t & ~63) * 8;

    const bf16* srcA[2]; const bf16* srcB[2];
#pragma unroll
    for (int r = 0; r < 2; r++) {
        int c = (r << 8) + t;
        int line = c >> 3;
        int s = (c & 7) ^ (line & 7);
        int row = line * 2 + (s >> 2);
        int j = s & 3;
        srcA[r] = A  + (size_t)(m0 + row) * DIMK + j * 8;
        srcB[r] = Wt + (size_t)(n0 + row) * DIMK + j * 8;
    }

    f32x4 acc[4][4];
#pragma unroll
    for (int m = 0; m < 4; m++)
#pragma unroll
        for (int nf = 0; nf < 4; nf++) acc[m][nf] = (f32x4){0.f,0.f,0.f,0.f};

#define PG_STAGE(BUF, K0) do { \
    gl16(srcA[0] + (K0), &Al[BUF][wbase]); \
    gl16(srcA[1] + (K0), &Al[BUF][2048 + wbase]); \
    gl16(srcB[0] + (K0), &Bl[BUF][wbase]); \
    gl16(srcB[1] + (K0), &Bl[BUF][2048 + wbase]); \
} while (0)

#define PG_COMP(BUF) do { \
    bfrag af[4]; \
    _Pragma("unroll") for (int m = 0; m < 4; m++) { \
        int row = rh + m * 16 + lr; int line = row >> 1; \
        af[m] = *(const bfrag*)&Al[BUF][line * 64 + ((((row & 1) << 2) | q) ^ (line & 7)) * 8]; \
    } \
    _Pragma("unroll") for (int nf = 0; nf < 4; nf++) { \
        int col = chf + nf * 16 + lr; int line = col >> 1; \
        bfrag bf_ = *(const bfrag*)&Bl[BUF][line * 64 + ((((col & 1) << 2) | q) ^ (line & 7)) * 8]; \
        _Pragma("unroll") for (int m = 0; m < 4; m++) \
            acc[m][nf] = __builtin_amdgcn_mfma_f32_16x16x32_bf16(af[m], bf_, acc[m][nf], 0, 0, 0); \
    } \
} while (0)

    PG_STAGE(0, 0);
    __syncthreads();
    for (int k0 = 0; k0 < DIMK; k0 += 2 * BK) {
        PG_STAGE(1, k0 + BK);
        PG_COMP(0);
        __syncthreads();
        if (k0 + 2 * BK < DIMK) PG_STAGE(0, k0 + 2 * BK);
        PG_COMP(1);
        __syncthreads();
    }
#undef PG_STAGE
#undef PG_COMP

#pragma unroll
    for (int nf = 0; nf < 4; nf++) {
        int col = n0 + chf + nf * 16 + lr;
        float bv = bias[col];
#pragma unroll
        for (int m = 0; m < 4; m++)
#pragma unroll
            for (int r = 0; r < 4; r++) {
                int row = m0 + rh + m * 16 + q * 4 + r;
                out[(size_t)row * DIMK + col] = acc[m][nf][r] + bv;
            }
    }
}

// Diagnostic fallback: absmax will report ws_size in MB (clean wrong answer, no crash)
__global__ void k_fallback(float v, float* __restrict__ out) {
    int i = blockIdx.x * 256 + threadIdx.x;
    out[i] = v;
}

extern "C" void kernel_launch(void* const* d_in, const int* in_sizes, int n_in,
                              void* d_out, int out_size, void* d_ws, size_t ws_size,
                              hipStream_t stream) {
    const float* x  = (const float*)d_in[0];
    const float* y  = (const float*)d_in[1];
    const float* We = (const float*)d_in[2];
    const float* Wg = (const float*)d_in[3];
    const float* bg = (const float*)d_in[4];
    const float* Wp = (const float*)d_in[5];
    const float* bp = (const float*)d_in[6];
    float* out = (float*)d_out;
    (void)in_sizes; (void)n_in; (void)out_size;

    char* ws = (char*)d_ws;
    // layout (bytes), all 16B-aligned:
    //   counts @ 0          (256)
    //   work   @ 256        (768)
    //   rowsP  @ 4096       (1,048,576)
    //   gA     @ 1,052,672  (1,048,576)
    //   gB     @ 2,101,248  (1,048,576)
    //   xb     @ 3,149,824  (16,777,216)
    //   yb     @ 19,927,040 (16,777,216)
    //   Web    @ 36,704,256 (201,326,592)   [now TRANSPOSED: [e][n][k] bf16]
    //   Wpb    @ 238,030,848 (8,388,608)    [now TRANSPOSED: [n][k] bf16]
    //   qbuf   @ 246,419,456 (16,777,216)  (also holds attention output)
    //   kvbuf  @ 263,196,672 (33,554,432)
    // total NEED = 296,751,104
    const size_t NEED = 296751104ULL;
    if (ws_size < NEED) {
        hipLaunchKernelGGL(k_fallback, dim3(NB * DIMK / 256), dim3(256), 0, stream,
                           (float)(ws_size >> 20), out);
        return;
    }
    int*   counts = (int*)ws;
    int2*  work   = (int2*)(ws + 256);
    int*   rowsP  = (int*)(ws + 4096);
    float* gA     = (float*)(ws + 1052672);
    float* gB     = (float*)(ws + 2101248);
    bf16*  xb     = (bf16*)(ws + 3149824);
    bf16*  yb     = (bf16*)(ws + 19927040);
    bf16*  Web    = (bf16*)(ws + 36704256);
    bf16*  Wpb    = (bf16*)(ws + 238030848);
    bf16*  qbuf   = (bf16*)(ws + 246419456);
    bf16*  kvbuf  = (bf16*)(ws + 263196672);

    const long long nxy = (long long)NB * DIMK;           // 8,388,608
    hipLaunchKernelGGL(k_cvt, dim3((unsigned)(nxy / 2048)), dim3(256), 0, stream, x,  xb,  nxy);
    hipLaunchKernelGGL(k_cvt, dim3((unsigned)(nxy / 2048)), dim3(256), 0, stream, y,  yb,  nxy);
    // We [E][DIMK][W3] f32  ->  Web [E][W3][DIMK] bf16
    hipLaunchKernelGGL(k_cvt_t, dim3(W3 / 64, DIMK / 64, NE), dim3(256), 0, stream,
                       We, Web, W3, DIMK, (long long)DIMK * W3, (long long)W3 * DIMK);
    // Wp [DIMK][DIMK] f32  ->  Wpb [n][k] bf16
    hipLaunchKernelGGL(k_cvt_t, dim3(DIMK / 64, DIMK / 64, 1), dim3(256), 0, stream,
                       Wp, Wpb, DIMK, DIMK, 0LL, 0LL);

    hipLaunchKernelGGL(k_zero, dim3(1), dim3(64), 0, stream, counts);
    hipLaunchKernelGGL(k_gate, dim3(NB), dim3(64), 0, stream, x, Wg, bg, counts, rowsP, gA, gB);
    hipLaunchKernelGGL(k_sched, dim3(1), dim3(64), 0, stream, counts, work);
    hipLaunchKernelGGL(k_moe, dim3(W3 / 128, WMAX), dim3(256), 0, stream,
                       xb, yb, Web, counts, rowsP, gA, gB, work, qbuf, kvbuf);
    hipLaunchKernelGGL(k_attn, dim3(NB), dim3(256), 0, stream, qbuf, kvbuf, qbuf);
    hipLaunchKernelGGL(k_gemm_bias, dim3(DIMK / 128, NB / 128), dim3(256), 0, stream,
                       qbuf, Wpb, bp, out);
}

// Round 2
// 1169.075 us; speedup vs baseline: 1.5576x; 1.0188x over previous
//
#include <hip/hip_runtime.h>
#include <hip/hip_bf16.h>
#include <math.h>

typedef __hip_bfloat16 bf16;
typedef unsigned short u16;
typedef __attribute__((ext_vector_type(4))) float f32x4;
typedef __attribute__((ext_vector_type(8))) __bf16 bfrag;

#define NB   4096
#define DIMK 2048
#define NE   8
#define NH   16
#define HDIM 128
#define W3   6144
#define BK   32
#define WMAX 96   // max work items: sum_p ceil(cnt_p/64) <= 64 + 27 = 91
#define QS   132  // attn q/k/v LDS row stride (floats)
#define ATT_SCALE 0.08838834764831845f

#define BAR()  __builtin_amdgcn_s_barrier()
#define SB0()  __builtin_amdgcn_sched_barrier(0)
#define PRIO(n) __builtin_amdgcn_s_setprio(n)

// ---- async global->LDS 16B (dest = wave-uniform base + lane*16) ----
__device__ __forceinline__ void gl16(const bf16* g, u16* l) {
    __builtin_amdgcn_global_load_lds(
        (const __attribute__((address_space(1))) void*)g,
        (__attribute__((address_space(3))) void*)l, 16, 0, 0);
}

// ---- f32 -> bf16 bulk conversion (8 elems/thread, vectorized) ----
__global__ __launch_bounds__(256)
void k_cvt(const float* __restrict__ src, bf16* __restrict__ dst, long long n) {
    long long i = ((long long)blockIdx.x * 256 + threadIdx.x) * 8;
    if (i + 8 <= n) {
        float4 a = *(const float4*)(src + i);
        float4 b = *(const float4*)(src + i + 4);
        bf16 o[8];
        o[0] = __float2bfloat16(a.x); o[1] = __float2bfloat16(a.y);
        o[2] = __float2bfloat16(a.z); o[3] = __float2bfloat16(a.w);
        o[4] = __float2bfloat16(b.x); o[5] = __float2bfloat16(b.y);
        o[6] = __float2bfloat16(b.z); o[7] = __float2bfloat16(b.w);
        *(uint4*)(dst + i) = *(uint4*)o;
    }
}

// ---- f32 -> bf16 TRANSPOSING conversion: dst[e][f][d] = bf16(src[e][d][f])
// 64x64 tiles via LDS; both global sides coalesced.
__global__ __launch_bounds__(256)
void k_cvt_t(const float* __restrict__ src, bf16* __restrict__ dst,
             int ldsrc, int lddst, long long srcE, long long dstE) {
    __shared__ u16 tile[64][65];
    int e = blockIdx.z;
    int d0 = blockIdx.y << 6, f0 = blockIdx.x << 6;
    int t = threadIdx.x;
    const float* S = src + (size_t)e * srcE + (size_t)d0 * ldsrc + f0;
    int dr = t >> 4, fc = (t & 15) << 2;
#pragma unroll
    for (int i = 0; i < 4; i++) {
        float4 v = *(const float4*)(S + (size_t)(dr + (i << 4)) * ldsrc + fc);
        bf16 b0 = __float2bfloat16(v.x), b1 = __float2bfloat16(v.y),
             b2 = __float2bfloat16(v.z), b3 = __float2bfloat16(v.w);
        u16* tp = &tile[dr + (i << 4)][fc];
        tp[0] = *(u16*)&b0; tp[1] = *(u16*)&b1;
        tp[2] = *(u16*)&b2; tp[3] = *(u16*)&b3;
    }
    __syncthreads();
    bf16* D = dst + (size_t)e * dstE + (size_t)f0 * lddst + d0;
#pragma unroll
    for (int r = 0; r < 2; r++) {
        int c = (r << 8) + t;
        int fr = c >> 3, chk = c & 7;
        u16 o[8];
#pragma unroll
        for (int j = 0; j < 8; j++) o[j] = tile[chk * 8 + j][fr];
        *(uint4*)(D + (size_t)fr * lddst + chk * 8) = *(uint4*)o;
    }
}

__global__ void k_zero(int* counts) {
    if (threadIdx.x < 64) counts[threadIdx.x] = 0;
}

// One wave per row, pure f32 (matches np reference selection): logits, softmax,
// top-2, append (row, gates) to PAIR list. Index-clamped so bad data cannot fault.
__global__ void k_gate(const float* __restrict__ x, const float* __restrict__ Wg,
                       const float* __restrict__ bg, int* __restrict__ counts,
                       int* __restrict__ rowsP, float* __restrict__ gA,
                       float* __restrict__ gB) {
    int b = blockIdx.x;
    int l = threadIdx.x;
    float acc[NE];
#pragma unroll
    for (int e = 0; e < NE; e++) acc[e] = 0.f;
    for (int i = 0; i < DIMK / 64; i++) {
        int d = i * 64 + l;
        float xv = x[(size_t)b * DIMK + d];
        const float* wrow = Wg + (size_t)d * NE;
#pragma unroll
        for (int e = 0; e < NE; e++) acc[e] += xv * wrow[e];
    }
#pragma unroll
    for (int e = 0; e < NE; e++)
        for (int off = 32; off > 0; off >>= 1) acc[e] += __shfl_down(acc[e], off);
    if (l == 0) {
        float p[NE]; float m = -1e30f;
        for (int e = 0; e < NE; e++) { p[e] = acc[e] + bg[e]; m = fmaxf(m, p[e]); }
        float s = 0.f;
        for (int e = 0; e < NE; e++) { p[e] = __expf(p[e] - m); s += p[e]; }
        float inv = 1.f / s;
        for (int e = 0; e < NE; e++) p[e] *= inv;
        int i1 = 0; float v1 = p[0];
        for (int e = 1; e < NE; e++) if (p[e] > v1) { v1 = p[e]; i1 = e; }   // first-max = jax tie rule
        int i2 = -1; float v2 = -1.f;
        for (int e = 0; e < NE; e++) if (e != i1 && p[e] > v2) { v2 = p[e]; i2 = e; }
        if (i2 < 0) i2 = (i1 + 1) & 7;   // NaN safety: never out of range
        int a, bb; float ga, gb;
        if (i1 < i2) { a = i1; bb = i2; ga = v1; gb = v2; }
        else         { a = i2; bb = i1; ga = v2; gb = v1; }
        int pid = a * NE + bb;
        pid = pid < 0 ? 0 : (pid > 63 ? 63 : pid);
        int pos = atomicAdd(&counts[pid], 1);
        if (pos < NB) {
            rowsP[pid * NB + pos] = b; gA[pid * NB + pos] = ga; gB[pid * NB + pos] = gb;
        }
    }
}

// Flatten (pair, row-tile) into a compact work list.
__global__ void k_sched(const int* __restrict__ counts, int2* __restrict__ work) {
    if (threadIdx.x == 0) {
        int w = 0;
        for (int p = 0; p < 64; p++) {
            int c = counts[p]; c = c > NB ? NB : c;
            for (int m = 0; m < c && w < WMAX; m += 64) work[w++] = make_int2(p, m);
        }
        for (; w < WMAX; w++) work[w] = make_int2(-1, 0);
    }
}

// Pair-grouped gather-GEMM over the full 6144 W columns.
// Wt layout: [e][n][k] bf16 (k-contiguous) -> pure DMA staging, no transpose.
// Tile: 64 rows x 128 cols x BK=32, 4 waves. Both-sides swizzled LDS (bank-conflict
// free, verified 0 conflicts R1). NEW: counted-vmcnt pipeline (T4) — raw s_barrier
// + s_waitcnt vmcnt(5), loads never drained to 0 in the main loop; stage issued
// right after the readers-done barrier; setprio(1) around MFMA clusters (T5).
__global__ __launch_bounds__(256, 3)
void k_moe(const bf16* __restrict__ xb, const bf16* __restrict__ yb,
           const bf16* __restrict__ Wt, const int* __restrict__ counts,
           const int* __restrict__ rowsP, const float* __restrict__ gAp,
           const float* __restrict__ gBp, const int2* __restrict__ work,
           bf16* __restrict__ qbuf, bf16* __restrict__ kvbuf) {
    int2 wi = work[blockIdx.y];
    if (wi.x < 0) return;
    int p = wi.x, m0 = wi.y;
    int eA = p >> 3, eB = p & 7;
    int cnt = counts[p]; cnt = cnt > NB ? NB : cnt;
    int n0 = blockIdx.x * 128;                // absolute W column
    const bf16* A = (n0 < DIMK) ? yb : xb;
    bf16* outp; int ldc, coff;
    if (n0 < DIMK) { outp = qbuf;  ldc = DIMK;     coff = n0; }
    else           { outp = kvbuf; ldc = 2 * DIMK; coff = n0 - DIMK; }

    __shared__ __align__(16) u16 Al[2][2048];        // 64 rows x 32 k, dbuf
    __shared__ __align__(16) u16 Bl[2][2][4096];     // [buf][expert][128 cols x 32 k]
    __shared__ int   rowb[64];
    __shared__ float ga_s[64], gb_s[64];

    int t = threadIdx.x;
    if (t < 64) {
        int mg = m0 + t;
        if (mg < cnt) {
            int rv = rowsP[p * NB + mg];
            rowb[t] = (rv >= 0 && rv < NB) ? rv : -1;
            ga_s[t] = gAp[p * NB + mg]; gb_s[t] = gBp[p * NB + mg];
        } else { rowb[t] = -1; ga_s[t] = 0.f; gb_s[t] = 0.f; }
    }
    __syncthreads();

    int lane = t & 63, w = t >> 6;
    int q = lane >> 4, lr = lane & 15;
    int wbase = (t & ~63) * 8;   // wave's LDS chunk base (u16 offset)

    // A staging source: 256 chunks (1 round). chunk t -> line t>>3, swizzled slot.
    int aline = t >> 3;
    int as_ = (t & 7) ^ (aline & 7);
    int atrow = aline * 2 + (as_ >> 2);
    int arowg = rowb[atrow];
    const bf16* srcA = A + (size_t)(arowg >= 0 ? arowg : 0) * DIMK + (as_ & 3) * 8;

    // B staging sources: 2 experts x 2 rounds (512 chunks each expert).
    const bf16* srcB0[2]; const bf16* srcB1[2];
#pragma unroll
    for (int r = 0; r < 2; r++) {
        int c = (r << 8) + t;
        int line = c >> 3;
        int s = (c & 7) ^ (line & 7);
        int col = line * 2 + (s >> 2);
        size_t off = (size_t)(n0 + col) * DIMK + (s & 3) * 8;
        srcB0[r] = Wt + (size_t)eA * W3 * DIMK + off;
        srcB1[r] = Wt + (size_t)eB * W3 * DIMK + off;
    }

    f32x4 acc0[2][4], acc1[2][4];   // [nf][m] for expert A / expert B
#pragma unroll
    for (int nf = 0; nf < 2; nf++)
#pragma unroll
        for (int m = 0; m < 4; m++) {
            acc0[nf][m] = (f32x4){0.f,0.f,0.f,0.f};
            acc1[nf][m] = (f32x4){0.f,0.f,0.f,0.f};
        }

#define MOE_STAGE(BUF, K0) do { \
    gl16(srcA + (K0),      &Al[BUF][wbase]); \
    gl16(srcB0[0] + (K0),  &Bl[BUF][0][wbase]); \
    gl16(srcB0[1] + (K0),  &Bl[BUF][0][2048 + wbase]); \
    gl16(srcB1[0] + (K0),  &Bl[BUF][1][wbase]); \
    gl16(srcB1[1] + (K0),  &Bl[BUF][1][2048 + wbase]); \
} while (0)

#define MOE_COMP(BUF) do { \
    bfrag af[4]; \
    _Pragma("unroll") for (int m = 0; m < 4; m++) { \
        int row = m * 16 + lr; int line = row >> 1; \
        af[m] = *(const bfrag*)&Al[BUF][line * 64 + ((((row & 1) << 2) | q) ^ (line & 7)) * 8]; \
    } \
    _Pragma("unroll") for (int nf = 0; nf < 2; nf++) { \
        int col = (w << 5) + (nf << 4) + lr; int line = col >> 1; \
        int bo = line * 64 + ((((col & 1) << 2) | q) ^ (line & 7)) * 8; \
        bfrag b0 = *(const bfrag*)&Bl[BUF][0][bo]; \
        bfrag b1 = *(const bfrag*)&Bl[BUF][1][bo]; \
        _Pragma("unroll") for (int m = 0; m < 4; m++) { \
            acc0[nf][m] = __builtin_amdgcn_mfma_f32_16x16x32_bf16(af[m], b0, acc0[nf][m], 0, 0, 0); \
            acc1[nf][m] = __builtin_amdgcn_mfma_f32_16x16x32_bf16(af[m], b1, acc1[nf][m], 0, 0, 0); \
        } \
    } \
} while (0)

    // ---- counted-vmcnt pipeline: 5 loads/stage, never drain to 0 in-loop ----
    MOE_STAGE(0, 0);
    MOE_STAGE(1, BK);
    asm volatile("s_waitcnt vmcnt(5)" ::: "memory");   // buf0's 5 landed
    BAR(); SB0();
    int k0 = 0;
    for (; k0 < DIMK - 2 * BK; k0 += 2 * BK) {
        PRIO(1); MOE_COMP(0); PRIO(0);
        BAR(); SB0();                                   // readers of buf0 done
        MOE_STAGE(0, k0 + 2 * BK);                      // in flight: buf1(5)+new(5)
        asm volatile("s_waitcnt vmcnt(5)" ::: "memory");// buf1's 5 landed
        BAR(); SB0();
        PRIO(1); MOE_COMP(1); PRIO(0);
        BAR(); SB0();                                   // readers of buf1 done
        MOE_STAGE(1, k0 + 3 * BK);
        asm volatile("s_waitcnt vmcnt(5)" ::: "memory");// next buf0's 5 landed
        BAR(); SB0();
    }
    // epilogue: buf0 = tile DIMK-64 (landed), buf1 = tile DIMK-32 (<=5 in flight)
    PRIO(1); MOE_COMP(0); PRIO(0);
    asm volatile("s_waitcnt vmcnt(0)" ::: "memory");
    BAR(); SB0();
    PRIO(1); MOE_COMP(1); PRIO(0);
#undef MOE_STAGE
#undef MOE_COMP

#pragma unroll
    for (int nf = 0; nf < 2; nf++) {
        int col = coff + (w << 5) + (nf << 4) + lr;
#pragma unroll
        for (int m = 0; m < 4; m++)
#pragma unroll
            for (int r = 0; r < 4; r++) {
                int tr = m * 16 + q * 4 + r;
                int rb = rowb[tr];
                if (rb >= 0)
                    outp[(size_t)rb * ldc + col] =
                        __float2bfloat16(ga_s[tr] * acc0[nf][m][r] + gb_s[tr] * acc1[nf][m][r]);
            }
    }
}

// Per-row 16x16 head-attention; aout may ALIAS qv (row fully read before write).
// PV restructured: thread owns (head hh, 8 consecutive dd) -> P hoisted to regs,
// V read as broadcast ds_read_b128 (5x fewer LDS instructions than scalar form).
__global__ __launch_bounds__(256)
void k_attn(const bf16* qv, const bf16* __restrict__ kv, bf16* aout) {
    int b = blockIdx.x;
    int t = threadIdx.x;
    __shared__ __align__(16) float qs[NH * QS];
    __shared__ __align__(16) float ks[NH * QS];
    __shared__ __align__(16) float vs[NH * QS];
    __shared__ float Ps[NH * 17];
    size_t qb = (size_t)b * DIMK;
    size_t kb = (size_t)b * (2 * DIMK);
    {   // vectorized bf16x8 loads (2048 elems per tensor = 256 threads x 8)
        uint4 q4 = *(const uint4*)(qv + qb + (size_t)t * 8);
        uint4 k4 = *(const uint4*)(kv + kb + (size_t)t * 8);
        uint4 v4 = *(const uint4*)(kv + kb + DIMK + (size_t)t * 8);
        const bf16* qp = (const bf16*)&q4;
        const bf16* kp = (const bf16*)&k4;
        const bf16* vp = (const bf16*)&v4;
        int hh = t >> 4, dd = (t & 15) << 3;
        float* qd = &qs[hh * QS + dd];
        float* kd = &ks[hh * QS + dd];
        float* vd = &vs[hh * QS + dd];
#pragma unroll
        for (int j = 0; j < 8; j++) {
            qd[j] = __bfloat162float(qp[j]);
            kd[j] = __bfloat162float(kp[j]);
            vd[j] = __bfloat162float(vp[j]);
        }
    }
    __syncthreads();
    int h = t >> 4, g = t & 15;
    float s = 0.f;
    for (int i = 0; i < HDIM / 4; i++) {
        float4 q4 = *(const float4*)&qs[h * QS + 4 * i];
        float4 k4 = *(const float4*)&ks[g * QS + 4 * i];
        s += q4.x * k4.x + q4.y * k4.y + q4.z * k4.z + q4.w * k4.w;
    }
    s *= ATT_SCALE;
    float m = s;
    for (int off = 8; off > 0; off >>= 1) m = fmaxf(m, __shfl_xor(m, off, 16));
    float p = __expf(s - m);
    float sum = p;
    for (int off = 8; off > 0; off >>= 1) sum += __shfl_xor(sum, off, 16);
    Ps[h * 17 + g] = p / sum;
    __syncthreads();
    {
        int hh = t & 15, dd0 = (t >> 4) * 8;   // 16 dd-groups x 16 heads = 256 threads
        float pr[16];
#pragma unroll
        for (int gg = 0; gg < 16; gg++) pr[gg] = Ps[hh * 17 + gg];
        float o[8];
#pragma unroll
        for (int r = 0; r < 8; r++) o[r] = 0.f;
#pragma unroll
        for (int gg = 0; gg < 16; gg++) {
            float4 v0 = *(const float4*)&vs[gg * QS + dd0];
            float4 v1 = *(const float4*)&vs[gg * QS + dd0 + 4];
            o[0] += pr[gg] * v0.x; o[1] += pr[gg] * v0.y;
            o[2] += pr[gg] * v0.z; o[3] += pr[gg] * v0.w;
            o[4] += pr[gg] * v1.x; o[5] += pr[gg] * v1.y;
            o[6] += pr[gg] * v1.z; o[7] += pr[gg] * v1.w;
        }
#pragma unroll
        for (int r = 0; r < 8; r++)   // flat n = dd*16+hh (swapaxes folded in)
            aout[(size_t)b * DIMK + (size_t)(dd0 + r) * 16 + hh] = __float2bfloat16(o[r]);
    }
}

// out(f32) = A(bf16) @ Wp + bp;  Wt layout [n][k] (k-contiguous).
// 128x128 tile, 4 waves; same counted-vmcnt pipeline as k_moe (4 loads/stage).
__global__ __launch_bounds__(256, 3)
void k_gemm_bias(const bf16* __restrict__ A, const bf16* __restrict__ Wt,
                 const float* __restrict__ bias, float* __restrict__ out) {
    int m0 = blockIdx.y * 128, n0 = blockIdx.x * 128;
    int t = threadIdx.x;
    __shared__ __align__(16) u16 Al[2][4096];   // 128 rows x 32 k, dbuf
    __shared__ __align__(16) u16 Bl[2][4096];   // 128 cols x 32 k, dbuf
    int lane = t & 63, w = t >> 6;
    int q = lane >> 4, lr = lane & 15;
    int rh = (w >> 1) << 6, chf = (w & 1) << 6;
    int wbase = (t & ~63) * 8;

    const bf16* srcA[2]; const bf16* srcB[2];
#pragma unroll
    for (int r = 0; r < 2; r++) {
        int c = (r << 8) + t;
        int line = c >> 3;
        int s = (c & 7) ^ (line & 7);
        int row = line * 2 + (s >> 2);
        int j = s & 3;
        srcA[r] = A  + (size_t)(m0 + row) * DIMK + j * 8;
        srcB[r] = Wt + (size_t)(n0 + row) * DIMK + j * 8;
    }

    f32x4 acc[4][4];
#pragma unroll
    for (int m = 0; m < 4; m++)
#pragma unroll
        for (int nf = 0; nf < 4; nf++) acc[m][nf] = (f32x4){0.f,0.f,0.f,0.f};

#define PG_STAGE(BUF, K0) do { \
    gl16(srcA[0] + (K0), &Al[BUF][wbase]); \
    gl16(srcA[1] + (K0), &Al[BUF][2048 + wbase]); \
    gl16(srcB[0] + (K0), &Bl[BUF][wbase]); \
    gl16(srcB[1] + (K0), &Bl[BUF][2048 + wbase]); \
} while (0)

#define PG_COMP(BUF) do { \
    bfrag af[4]; \
    _Pragma("unroll") for (int m = 0; m < 4; m++) { \
        int row = rh + m * 16 + lr; int line = row >> 1; \
        af[m] = *(const bfrag*)&Al[BUF][line * 64 + ((((row & 1) << 2) | q) ^ (line & 7)) * 8]; \
    } \
    _Pragma("unroll") for (int nf = 0; nf < 4; nf++) { \
        int col = chf + nf * 16 + lr; int line = col >> 1; \
        bfrag bf_ = *(const bfrag*)&Bl[BUF][line * 64 + ((((col & 1) << 2) | q) ^ (line & 7)) * 8]; \
        _Pragma("unroll") for (int m = 0; m < 4; m++) \
            acc[m][nf] = __builtin_amdgcn_mfma_f32_16x16x32_bf16(af[m], bf_, acc[m][nf], 0, 0, 0); \
    } \
} while (0)

    PG_STAGE(0, 0);
    PG_STAGE(1, BK);
    asm volatile("s_waitcnt vmcnt(4)" ::: "memory");
    BAR(); SB0();
    int k0 = 0;
    for (; k0 < DIMK - 2 * BK; k0 += 2 * BK) {
        PRIO(1); PG_COMP(0); PRIO(0);
        BAR(); SB0();
        PG_STAGE(0, k0 + 2 * BK);
        asm volatile("s_waitcnt vmcnt(4)" ::: "memory");
        BAR(); SB0();
        PRIO(1); PG_COMP(1); PRIO(0);
        BAR(); SB0();
        PG_STAGE(1, k0 + 3 * BK);
        asm volatile("s_waitcnt vmcnt(4)" ::: "memory");
        BAR(); SB0();
    }
    PRIO(1); PG_COMP(0); PRIO(0);
    asm volatile("s_waitcnt vmcnt(0)" ::: "memory");
    BAR(); SB0();
    PRIO(1); PG_COMP(1); PRIO(0);
#undef PG_STAGE
#undef PG_COMP

#pragma unroll
    for (int nf = 0; nf < 4; nf++) {
        int col = n0 + chf + nf * 16 + lr;
        float bv = bias[col];
#pragma unroll
        for (int m = 0; m < 4; m++)
#pragma unroll
            for (int r = 0; r < 4; r++) {
                int row = m0 + rh + m * 16 + q * 4 + r;
                out[(size_t)row * DIMK + col] = acc[m][nf][r] + bv;
            }
    }
}

// Diagnostic fallback: absmax will report ws_size in MB (clean wrong answer, no crash)
__global__ void k_fallback(float v, float* __restrict__ out) {
    int i = blockIdx.x * 256 + threadIdx.x;
    out[i] = v;
}

extern "C" void kernel_launch(void* const* d_in, const int* in_sizes, int n_in,
                              void* d_out, int out_size, void* d_ws, size_t ws_size,
                              hipStream_t stream) {
    const float* x  = (const float*)d_in[0];
    const float* y  = (const float*)d_in[1];
    const float* We = (const float*)d_in[2];
    const float* Wg = (const float*)d_in[3];
    const float* bg = (const float*)d_in[4];
    const float* Wp = (const float*)d_in[5];
    const float* bp = (const float*)d_in[6];
    float* out = (float*)d_out;
    (void)in_sizes; (void)n_in; (void)out_size;

    char* ws = (char*)d_ws;
    // layout (bytes), all 16B-aligned:
    //   counts @ 0          (256)
    //   work   @ 256        (768)
    //   rowsP  @ 4096       (1,048,576)
    //   gA     @ 1,052,672  (1,048,576)
    //   gB     @ 2,101,248  (1,048,576)
    //   xb     @ 3,149,824  (16,777,216)
    //   yb     @ 19,927,040 (16,777,216)
    //   Web    @ 36,704,256 (201,326,592)   [TRANSPOSED: [e][n][k] bf16]
    //   Wpb    @ 238,030,848 (8,388,608)    [TRANSPOSED: [n][k] bf16]
    //   qbuf   @ 246,419,456 (16,777,216)  (also holds attention output)
    //   kvbuf  @ 263,196,672 (33,554,432)
    // total NEED = 296,751,104
    const size_t NEED = 296751104ULL;
    if (ws_size < NEED) {
        hipLaunchKernelGGL(k_fallback, dim3(NB * DIMK / 256), dim3(256), 0, stream,
                           (float)(ws_size >> 20), out);
        return;
    }
    int*   counts = (int*)ws;
    int2*  work   = (int2*)(ws + 256);
    int*   rowsP  = (int*)(ws + 4096);
    float* gA     = (float*)(ws + 1052672);
    float* gB     = (float*)(ws + 2101248);
    bf16*  xb     = (bf16*)(ws + 3149824);
    bf16*  yb     = (bf16*)(ws + 19927040);
    bf16*  Web    = (bf16*)(ws + 36704256);
    bf16*  Wpb    = (bf16*)(ws + 238030848);
    bf16*  qbuf   = (bf16*)(ws + 246419456);
    bf16*  kvbuf  = (bf16*)(ws + 263196672);

    const long long nxy = (long long)NB * DIMK;           // 8,388,608
    hipLaunchKernelGGL(k_cvt, dim3((unsigned)(nxy / 2048)), dim3(256), 0, stream, x,  xb,  nxy);
    hipLaunchKernelGGL(k_cvt, dim3((unsigned)(nxy / 2048)), dim3(256), 0, stream, y,  yb,  nxy);
    // We [E][DIMK][W3] f32  ->  Web [E][W3][DIMK] bf16
    hipLaunchKernelGGL(k_cvt_t, dim3(W3 / 64, DIMK / 64, NE), dim3(256), 0, stream,
                       We, Web, W3, DIMK, (long long)DIMK * W3, (long long)W3 * DIMK);
    // Wp [DIMK][DIMK] f32  ->  Wpb [n][k] bf16
    hipLaunchKernelGGL(k_cvt_t, dim3(DIMK / 64, DIMK / 64, 1), dim3(256), 0, stream,
                       Wp, Wpb, DIMK, DIMK, 0LL, 0LL);

    hipLaunchKernelGGL(k_zero, dim3(1), dim3(64), 0, stream, counts);
    hipLaunchKernelGGL(k_gate, dim3(NB), dim3(64), 0, stream, x, Wg, bg, counts, rowsP, gA, gB);
    hipLaunchKernelGGL(k_sched, dim3(1), dim3(64), 0, stream, counts, work);
    hipLaunchKernelGGL(k_moe, dim3(W3 / 128, WMAX), dim3(256), 0, stream,
                       xb, yb, Web, counts, rowsP, gA, gB, work, qbuf, kvbuf);
    hipLaunchKernelGGL(k_attn, dim3(NB), dim3(256), 0, stream, qbuf, kvbuf, qbuf);
    hipLaunchKernelGGL(k_gemm_bias, dim3(DIMK / 128, NB / 128), dim3(256), 0, stream,
                       qbuf, Wpb, bp, out);
}